// Round 2
// baseline (247.006 us; speedup 1.0000x reference)
//
#include <hip/hip_runtime.h>
#include <hip/hip_bf16.h>
#include <stdint.h>

#define LOG2E 1.44269504088896340736f

typedef float f32x4 __attribute__((ext_vector_type(4)));
typedef __bf16 bf16x8 __attribute__((ext_vector_type(8)));

__device__ __forceinline__ void g2lds16(const void* g, void* l) {
  __builtin_amdgcn_global_load_lds(
      (__attribute__((address_space(1))) unsigned int*)g,
      (__attribute__((address_space(3))) unsigned int*)l,
      16, 0, 0);
}

__device__ __forceinline__ unsigned short f2bf_u(float f) {
  __bf16 h = (__bf16)f;
  return __builtin_bit_cast(unsigned short, h);
}

// ---------------------------------------------------------------------------
// prep_hidden: one block per row i (B*S = 8192). Converts hidden row to bf16,
// computes xu = h.U[:1024]+U[1024], xv = h.V[:1024]+V[1024].
// Stores aL[i] = (xu/8)*log2e, vArr[i] = xv.
// ---------------------------------------------------------------------------
__global__ void __launch_bounds__(256) prep_hidden(
    const float* __restrict__ hidden, const float* __restrict__ U,
    const float* __restrict__ V, unsigned short* __restrict__ hbf,
    float* __restrict__ aL, float* __restrict__ vArr) {
  int row = blockIdx.x;
  int tid = threadIdx.x;
  const float* hr = hidden + (size_t)row * 1024;
  float4 x = *(const float4*)&hr[tid * 4];
  float4 u = *(const float4*)&U[tid * 4];
  float4 v = *(const float4*)&V[tid * 4];
  ushort4 hb;
  hb.x = f2bf_u(x.x); hb.y = f2bf_u(x.y); hb.z = f2bf_u(x.z); hb.w = f2bf_u(x.w);
  *(ushort4*)&hbf[(size_t)row * 1024 + tid * 4] = hb;
  float su = x.x * u.x + x.y * u.y + x.z * u.z + x.w * u.w;
  float sv = x.x * v.x + x.y * v.y + x.z * v.z + x.w * v.w;
  for (int off = 32; off > 0; off >>= 1) {
    su += __shfl_down(su, off);
    sv += __shfl_down(sv, off);
  }
  __shared__ float red[8];
  int lane = tid & 63, w = tid >> 6;
  if (lane == 0) { red[w] = su; red[4 + w] = sv; }
  __syncthreads();
  if (tid == 0) {
    float xu = red[0] + red[1] + red[2] + red[3] + U[1024];
    float xv = red[4] + red[5] + red[6] + red[7] + V[1024];
    aL[row] = xu * 0.125f * LOG2E;
    vArr[row] = xv;
  }
}

// ---------------------------------------------------------------------------
__global__ void __launch_bounds__(256) prep_w(const float* __restrict__ w,
                                              unsigned short* __restrict__ wbf) {
  int idx = (blockIdx.x * 256 + threadIdx.x) * 4;
  float4 x = *(const float4*)&w[idx];
  ushort4 hb;
  hb.x = f2bf_u(x.x); hb.y = f2bf_u(x.y); hb.z = f2bf_u(x.z); hb.w = f2bf_u(x.w);
  *(ushort4*)&wbf[idx] = hb;
}

__global__ void __launch_bounds__(256) prep_mask(const float* __restrict__ mask,
                                                 float* __restrict__ mL) {
  int i = blockIdx.x * 256 + threadIdx.x;
  mL[i] = mask[i] * LOG2E;
}

// ---------------------------------------------------------------------------
// stats: one block per row i. mx2[i] = max_t(aL*v+mL) (log2 domain),
// invZ[i] = 1/sum_t exp2(... - mx2).
// ---------------------------------------------------------------------------
__global__ void __launch_bounds__(256) stats(
    const float* __restrict__ aL, const float* __restrict__ vArr,
    const float* __restrict__ mL, float* __restrict__ mx2,
    float* __restrict__ invZ) {
  int i = blockIdx.x;
  int tbase = (i >> 11) << 11;
  int tid = threadIdx.x;
  float a = aL[i];
  float mloc = -3.0e38f;
#pragma unroll
  for (int c = 0; c < 8; ++c) {
    int t = c * 256 + tid;
    mloc = fmaxf(mloc, fmaf(a, vArr[tbase + t], mL[tbase + t]));
  }
  for (int off = 32; off > 0; off >>= 1) mloc = fmaxf(mloc, __shfl_down(mloc, off));
  __shared__ float red[8];
  int lane = tid & 63, w = tid >> 6;
  if (lane == 0) red[w] = mloc;
  __syncthreads();
  float mx = fmaxf(fmaxf(red[0], red[1]), fmaxf(red[2], red[3]));
  float z = 0.f;
#pragma unroll
  for (int c = 0; c < 8; ++c) {
    int t = c * 256 + tid;
    z += __builtin_amdgcn_exp2f(fmaf(a, vArr[tbase + t], mL[tbase + t]) - mx);
  }
  for (int off = 32; off > 0; off >>= 1) z += __shfl_down(z, off);
  if (lane == 0) red[4 + w] = z;
  __syncthreads();
  if (tid == 0) {
    mx2[i] = mx;
    invZ[i] = 1.0f / (red[4] + red[5] + red[6] + red[7]);
  }
}

// ---------------------------------------------------------------------------
// pgen: materialize P' (bf16, invZ folded): one block per global row i.
// P'[i][t] = invZ[i] * exp2(aL[i]*vArr[tb+t] + mL[tb+t] - mx2[i])
// ---------------------------------------------------------------------------
__global__ void __launch_bounds__(256) pgen(
    const float* __restrict__ aL, const float* __restrict__ vArr,
    const float* __restrict__ mL, const float* __restrict__ mx2,
    const float* __restrict__ invZ, unsigned short* __restrict__ p) {
  int row = blockIdx.x;
  int tb = (row >> 11) << 11;
  int t0 = threadIdx.x * 8;
  float a = aL[row], mx = mx2[row], iz = invZ[row];
  float4 v0 = *(const float4*)&vArr[tb + t0];
  float4 v1 = *(const float4*)&vArr[tb + t0 + 4];
  float4 m0 = *(const float4*)&mL[tb + t0];
  float4 m1 = *(const float4*)&mL[tb + t0 + 4];
  float pe[8];
  pe[0] = iz * __builtin_amdgcn_exp2f(fmaf(a, v0.x, m0.x) - mx);
  pe[1] = iz * __builtin_amdgcn_exp2f(fmaf(a, v0.y, m0.y) - mx);
  pe[2] = iz * __builtin_amdgcn_exp2f(fmaf(a, v0.z, m0.z) - mx);
  pe[3] = iz * __builtin_amdgcn_exp2f(fmaf(a, v0.w, m0.w) - mx);
  pe[4] = iz * __builtin_amdgcn_exp2f(fmaf(a, v1.x, m1.x) - mx);
  pe[5] = iz * __builtin_amdgcn_exp2f(fmaf(a, v1.y, m1.y) - mx);
  pe[6] = iz * __builtin_amdgcn_exp2f(fmaf(a, v1.z, m1.z) - mx);
  pe[7] = iz * __builtin_amdgcn_exp2f(fmaf(a, v1.w, m1.w) - mx);
  bf16x8 o;
#pragma unroll
  for (int u = 0; u < 8; ++u) o[u] = (__bf16)pe[u];
  *(bf16x8*)&p[(size_t)row * 2048 + t0] = o;
}

// ---------------------------------------------------------------------------
// gemm_vl: VL = hbf @ Wbf^T + bias, stored TRANSPOSED bf16: vlt[h][i],
// pitch 8192. M=8192 N=1024 K=1024. Tile 128(M)x64(N), BK=32 -> 1024 blocks
// (4 blocks/CU). Waves 2x2: each 64(M)x32(N) via 4x2 16x16x32 MFMA.
// ---------------------------------------------------------------------------
__global__ void __launch_bounds__(256) gemm_vl(
    const unsigned short* __restrict__ hbf, const unsigned short* __restrict__ wbf,
    const float* __restrict__ bias, unsigned short* __restrict__ vlt) {
  __shared__ __align__(16) char sA[128 * 64];
  __shared__ __align__(16) char sB[64 * 64];
  int tid = threadIdx.x;
  int lane = tid & 63, wave = tid >> 6;
  int m0 = blockIdx.y * 128;
  int n0 = blockIdx.x * 64;
  int sr = lane >> 2, sc = lane & 3;
  int wr = wave >> 1, wc = wave & 1;
  int m_ = lane & 15, q = lane >> 4;
  int e = (m_ >> 1) & 3;
  const char* arp = sA + ((wr * 64 + m_) * 64) + ((q ^ e) * 16);
  const char* brp = sB + ((wc * 32 + m_) * 64) + ((q ^ e) * 16);
  f32x4 acc[4][2] = {};
  for (int k0 = 0; k0 < 1024; k0 += 32) {
    __syncthreads();
#pragma unroll
    for (int ii = 0; ii < 2; ++ii) {
      int r0 = wave * 32 + ii * 16;
      int r = r0 + sr;
      int cg = sc ^ ((r >> 1) & 3);
      g2lds16(hbf + ((size_t)(m0 + r) * 1024 + k0 + cg * 8), sA + r0 * 64);
    }
    {
      int r0 = wave * 16;
      int r = r0 + sr;
      int cg = sc ^ ((r >> 1) & 3);
      g2lds16(wbf + ((size_t)(n0 + r) * 1024 + k0 + cg * 8), sB + r0 * 64);
    }
    __syncthreads();
    bf16x8 af[4], bfr[2];
#pragma unroll
    for (int i = 0; i < 4; ++i) af[i] = *(const bf16x8*)(arp + i * 1024);
#pragma unroll
    for (int j = 0; j < 2; ++j) bfr[j] = *(const bf16x8*)(brp + j * 1024);
#pragma unroll
    for (int i = 0; i < 4; ++i)
#pragma unroll
      for (int j = 0; j < 2; ++j)
        acc[i][j] = __builtin_amdgcn_mfma_f32_16x16x32_bf16(af[i], bfr[j], acc[i][j], 0, 0, 0);
  }
#pragma unroll
  for (int jt = 0; jt < 2; ++jt) {
    int j = n0 + wc * 32 + jt * 16 + m_;
    float bj = bias[j];
#pragma unroll
    for (int it = 0; it < 4; ++it) {
      int i = m0 + wr * 64 + it * 16 + q * 4;
      f32x4 a = acc[it][jt];
      ushort4 o;
      o.x = f2bf_u(a.x + bj); o.y = f2bf_u(a.y + bj);
      o.z = f2bf_u(a.z + bj); o.w = f2bf_u(a.w + bj);
      *(ushort4*)&vlt[(size_t)j * 8192 + i] = o;
    }
  }
}

// ---------------------------------------------------------------------------
// attn: pure GEMM C += P' @ VL^T-slice. Grid (8 h-tiles, 64 s-tiles, 2 k-halves)
// = 1024 blocks. 128x128 tile, BK=32, both operands via global_load_lds.
// Epilogue: fp32 atomic add (out pre-zeroed; invZ already folded into P').
// ---------------------------------------------------------------------------
__global__ void __launch_bounds__(256) attn(
    const unsigned short* __restrict__ p, const unsigned short* __restrict__ vlt,
    float* __restrict__ out) {
  __shared__ __align__(16) char sA[128 * 64];
  __shared__ __align__(16) char sB[128 * 64];
  int tid = threadIdx.x;
  int lane = tid & 63, wave = tid >> 6;
  int i0 = blockIdx.y * 128;   // global s-row (batch-major, 128 | 2048)
  int h0 = blockIdx.x * 128;
  int b = i0 >> 11;
  size_t poff = (size_t)blockIdx.z * 1024;           // t-offset in P row
  size_t toff = ((size_t)b << 11) + poff;            // t-offset in vlt row
  int sr = lane >> 2, sc = lane & 3;
  int wr = wave >> 1, wc = wave & 1;
  int m_ = lane & 15, q = lane >> 4;
  int e = (m_ >> 1) & 3;
  const char* arp = sA + ((wr * 64 + m_) * 64) + ((q ^ e) * 16);
  const char* brp = sB + ((wc * 64 + m_) * 64) + ((q ^ e) * 16);
  f32x4 acc[4][4] = {};
  for (int k0 = 0; k0 < 1024; k0 += 32) {
    __syncthreads();
#pragma unroll
    for (int ii = 0; ii < 2; ++ii) {
      int r0 = wave * 32 + ii * 16;
      int r = r0 + sr;
      int cg = sc ^ ((r >> 1) & 3);
      g2lds16(p + ((size_t)(i0 + r) * 2048 + poff + k0 + cg * 8), sA + r0 * 64);
      g2lds16(vlt + ((size_t)(h0 + r) * 8192 + toff + k0 + cg * 8), sB + r0 * 64);
    }
    __syncthreads();
    bf16x8 af[4], bfr[4];
#pragma unroll
    for (int i = 0; i < 4; ++i) af[i] = *(const bf16x8*)(arp + i * 1024);
#pragma unroll
    for (int j = 0; j < 4; ++j) bfr[j] = *(const bf16x8*)(brp + j * 1024);
#pragma unroll
    for (int i = 0; i < 4; ++i)
#pragma unroll
      for (int j = 0; j < 4; ++j)
        acc[i][j] = __builtin_amdgcn_mfma_f32_16x16x32_bf16(af[i], bfr[j], acc[i][j], 0, 0, 0);
  }
#pragma unroll
  for (int it = 0; it < 4; ++it) {
    int gi = i0 + wr * 64 + it * 16 + q * 4;
#pragma unroll
    for (int jt = 0; jt < 4; ++jt) {
      int h = h0 + wc * 64 + jt * 16 + m_;
      f32x4 a = acc[it][jt];
      unsafeAtomicAdd(&out[(size_t)(gi + 0) * 1024 + h], a.x);
      unsafeAtomicAdd(&out[(size_t)(gi + 1) * 1024 + h], a.y);
      unsafeAtomicAdd(&out[(size_t)(gi + 2) * 1024 + h], a.z);
      unsafeAtomicAdd(&out[(size_t)(gi + 3) * 1024 + h], a.w);
    }
  }
}

// ---------------------------------------------------------------------------
// ws layout (peak ~50.5 MB):
//   [0, 33.5MB)        P' (bf16)  -- overlaps hbf[0,16MB)+wbf[16,18MB), which
//                                    are dead after gemm_vl and before pgen
//   [33.5MB, 50.3MB)   vlt (bf16, [1024][8192])
//   [50.3MB, 50.5MB)   aL, vArr, mL, mx2, invZ (5 x 32KB fp32)
// ---------------------------------------------------------------------------
extern "C" void kernel_launch(void* const* d_in, const int* in_sizes, int n_in,
                              void* d_out, int out_size, void* d_ws, size_t ws_size,
                              hipStream_t stream) {
  const float* hidden = (const float*)d_in[0];
  const float* mask   = (const float*)d_in[1];
  const float* vw     = (const float*)d_in[2];
  const float* vb     = (const float*)d_in[3];
  const float* U      = (const float*)d_in[4];
  const float* V      = (const float*)d_in[5];
  float* out = (float*)d_out;
  char* ws = (char*)d_ws;

  unsigned short* P   = (unsigned short*)ws;                   // 33,554,432 B
  unsigned short* hbf = (unsigned short*)ws;                   // 16,777,216 B (dies before P written)
  unsigned short* wbf = (unsigned short*)(ws + 16777216);      //  2,097,152 B (dies before P written)
  unsigned short* vlt = (unsigned short*)(ws + 33554432);      // 16,777,216 B
  float* aL   = (float*)(ws + 50331648);
  float* vArr = aL + 8192;
  float* mLa  = vArr + 8192;
  float* mxa  = mLa + 8192;
  float* iZ   = mxa + 8192;

  hipMemsetAsync(d_out, 0, (size_t)out_size * sizeof(float), stream);
  prep_hidden<<<8192, 256, 0, stream>>>(hidden, U, V, hbf, aL, vArr);
  prep_w<<<1024, 256, 0, stream>>>(vw, wbf);
  prep_mask<<<32, 256, 0, stream>>>(mask, mLa);
  stats<<<8192, 256, 0, stream>>>(aL, vArr, mLa, mxa, iZ);
  gemm_vl<<<dim3(16, 64), 256, 0, stream>>>(hbf, wbf, vb, vlt);
  pgen<<<8192, 256, 0, stream>>>(aL, vArr, mLa, mxa, iZ, P);
  attn<<<dim3(8, 64, 2), 256, 0, stream>>>(P, vlt, out);
}

// Round 3
// 189.598 us; speedup vs baseline: 1.3028x; 1.3028x over previous
//
#include <hip/hip_runtime.h>
#include <hip/hip_bf16.h>
#include <stdint.h>

#define LOG2E 1.44269504088896340736f

typedef float f32x4 __attribute__((ext_vector_type(4)));
typedef __bf16 bf16x8 __attribute__((ext_vector_type(8)));

__device__ __forceinline__ void g2lds16(const void* g, void* l) {
  __builtin_amdgcn_global_load_lds(
      (__attribute__((address_space(1))) unsigned int*)g,
      (__attribute__((address_space(3))) unsigned int*)l,
      16, 0, 0);
}

__device__ __forceinline__ unsigned short f2bf_u(float f) {
  __bf16 h = (__bf16)f;
  return __builtin_bit_cast(unsigned short, h);
}

// ---------------------------------------------------------------------------
// prep_hidden: one block per row i (B*S = 8192). Converts hidden row to bf16,
// computes xu = h.U[:1024]+U[1024], xv = h.V[:1024]+V[1024].
// Stores aL[i] = (xu/8)*log2e, vArr[i] = xv.
// ---------------------------------------------------------------------------
__global__ void __launch_bounds__(256) prep_hidden(
    const float* __restrict__ hidden, const float* __restrict__ U,
    const float* __restrict__ V, unsigned short* __restrict__ hbf,
    float* __restrict__ aL, float* __restrict__ vArr) {
  int row = blockIdx.x;
  int tid = threadIdx.x;
  const float* hr = hidden + (size_t)row * 1024;
  float4 x = *(const float4*)&hr[tid * 4];
  float4 u = *(const float4*)&U[tid * 4];
  float4 v = *(const float4*)&V[tid * 4];
  ushort4 hb;
  hb.x = f2bf_u(x.x); hb.y = f2bf_u(x.y); hb.z = f2bf_u(x.z); hb.w = f2bf_u(x.w);
  *(ushort4*)&hbf[(size_t)row * 1024 + tid * 4] = hb;
  float su = x.x * u.x + x.y * u.y + x.z * u.z + x.w * u.w;
  float sv = x.x * v.x + x.y * v.y + x.z * v.z + x.w * v.w;
  for (int off = 32; off > 0; off >>= 1) {
    su += __shfl_down(su, off);
    sv += __shfl_down(sv, off);
  }
  __shared__ float red[8];
  int lane = tid & 63, w = tid >> 6;
  if (lane == 0) { red[w] = su; red[4 + w] = sv; }
  __syncthreads();
  if (tid == 0) {
    float xu = red[0] + red[1] + red[2] + red[3] + U[1024];
    float xv = red[4] + red[5] + red[6] + red[7] + V[1024];
    aL[row] = xu * 0.125f * LOG2E;
    vArr[row] = xv;
  }
}

// ---------------------------------------------------------------------------
__global__ void __launch_bounds__(256) prep_w(const float* __restrict__ w,
                                              unsigned short* __restrict__ wbf) {
  int idx = (blockIdx.x * 256 + threadIdx.x) * 4;
  float4 x = *(const float4*)&w[idx];
  ushort4 hb;
  hb.x = f2bf_u(x.x); hb.y = f2bf_u(x.y); hb.z = f2bf_u(x.z); hb.w = f2bf_u(x.w);
  *(ushort4*)&wbf[idx] = hb;
}

__global__ void __launch_bounds__(256) prep_mask(const float* __restrict__ mask,
                                                 float* __restrict__ mL) {
  int i = blockIdx.x * 256 + threadIdx.x;
  mL[i] = mask[i] * LOG2E;
}

// ---------------------------------------------------------------------------
// statsP: one block per row i. Computes row max and sum in log2 domain, then
// writes P'[i][t] = invZ*exp2(aL*v+mL-mx) as bf16 (exp values kept in regs
// between the sum pass and the write).
// Each thread owns 8 consecutive t (t0 = tid*8).
// ---------------------------------------------------------------------------
__global__ void __launch_bounds__(256) statsP(
    const float* __restrict__ aL, const float* __restrict__ vArr,
    const float* __restrict__ mL, unsigned short* __restrict__ p) {
  int i = blockIdx.x;
  int tb = (i >> 11) << 11;
  int tid = threadIdx.x;
  int t0 = tid * 8;
  float a = aL[i];
  float4 v0 = *(const float4*)&vArr[tb + t0];
  float4 v1 = *(const float4*)&vArr[tb + t0 + 4];
  float4 m0 = *(const float4*)&mL[tb + t0];
  float4 m1 = *(const float4*)&mL[tb + t0 + 4];
  float s[8];
  s[0] = fmaf(a, v0.x, m0.x); s[1] = fmaf(a, v0.y, m0.y);
  s[2] = fmaf(a, v0.z, m0.z); s[3] = fmaf(a, v0.w, m0.w);
  s[4] = fmaf(a, v1.x, m1.x); s[5] = fmaf(a, v1.y, m1.y);
  s[6] = fmaf(a, v1.z, m1.z); s[7] = fmaf(a, v1.w, m1.w);
  float mloc = s[0];
#pragma unroll
  for (int u = 1; u < 8; ++u) mloc = fmaxf(mloc, s[u]);
  for (int off = 32; off > 0; off >>= 1) mloc = fmaxf(mloc, __shfl_down(mloc, off));
  __shared__ float red[8];
  __shared__ float bc[2];
  int lane = tid & 63, w = tid >> 6;
  if (lane == 0) red[w] = mloc;
  __syncthreads();
  if (tid == 0) bc[0] = fmaxf(fmaxf(red[0], red[1]), fmaxf(red[2], red[3]));
  __syncthreads();
  float mx = bc[0];
  float pe[8];
  float z = 0.f;
#pragma unroll
  for (int u = 0; u < 8; ++u) {
    pe[u] = __builtin_amdgcn_exp2f(s[u] - mx);
    z += pe[u];
  }
  for (int off = 32; off > 0; off >>= 1) z += __shfl_down(z, off);
  if (lane == 0) red[4 + w] = z;
  __syncthreads();
  if (tid == 0) bc[1] = 1.0f / (red[4] + red[5] + red[6] + red[7]);
  __syncthreads();
  float iz = bc[1];
  bf16x8 o;
#pragma unroll
  for (int u = 0; u < 8; ++u) o[u] = (__bf16)(iz * pe[u]);
  *(bf16x8*)&p[(size_t)i * 2048 + t0] = o;
}

// ---------------------------------------------------------------------------
// gemm_vl: VL = hbf @ Wbf^T + bias, stored TRANSPOSED bf16: vlt[h][i],
// pitch 8192. M=8192 N=1024 K=1024. 128x128 tile, BK=32, 512 blocks.
// XCD swizzle: xcd = id&7 gets m-tiles [xcd*8, xcd*8+8) x all 8 n-tiles
// -> per-XCD L2 set = 2MB wbf + 2MB hbf.
// ---------------------------------------------------------------------------
__global__ void __launch_bounds__(256) gemm_vl(
    const unsigned short* __restrict__ hbf, const unsigned short* __restrict__ wbf,
    const float* __restrict__ bias, unsigned short* __restrict__ vlt) {
  __shared__ __align__(16) char sA[128 * 64];
  __shared__ __align__(16) char sB[128 * 64];
  int tid = threadIdx.x;
  int lane = tid & 63, wave = tid >> 6;
  int pid = blockIdx.x;
  int xcd = pid & 7, kk = pid >> 3;
  int m0 = (xcd * 8 + (kk >> 3)) * 128;
  int n0 = (kk & 7) * 128;
  int sr = lane >> 2, sc = lane & 3;
  int wr = wave >> 1, wc = wave & 1;
  int m_ = lane & 15, q = lane >> 4;
  int e = (m_ >> 1) & 3;
  const char* arp = sA + ((wr * 64 + m_) * 64) + ((q ^ e) * 16);
  const char* brp = sB + ((wc * 64 + m_) * 64) + ((q ^ e) * 16);
  f32x4 acc[4][4] = {};
  for (int k0 = 0; k0 < 1024; k0 += 32) {
    __syncthreads();
#pragma unroll
    for (int ii = 0; ii < 2; ++ii) {
      int r0 = wave * 32 + ii * 16;
      int r = r0 + sr;
      int cg = sc ^ ((r >> 1) & 3);
      g2lds16(hbf + ((size_t)(m0 + r) * 1024 + k0 + cg * 8), sA + r0 * 64);
      g2lds16(wbf + ((size_t)(n0 + r) * 1024 + k0 + cg * 8), sB + r0 * 64);
    }
    __syncthreads();
    bf16x8 af[4], bfr[4];
#pragma unroll
    for (int i = 0; i < 4; ++i) af[i] = *(const bf16x8*)(arp + i * 1024);
#pragma unroll
    for (int j = 0; j < 4; ++j) bfr[j] = *(const bf16x8*)(brp + j * 1024);
#pragma unroll
    for (int i = 0; i < 4; ++i)
#pragma unroll
      for (int j = 0; j < 4; ++j)
        acc[i][j] = __builtin_amdgcn_mfma_f32_16x16x32_bf16(af[i], bfr[j], acc[i][j], 0, 0, 0);
  }
#pragma unroll
  for (int jt = 0; jt < 4; ++jt) {
    int j = n0 + wc * 64 + jt * 16 + m_;
    float bj = bias[j];
#pragma unroll
    for (int it = 0; it < 4; ++it) {
      int i = m0 + wr * 64 + it * 16 + q * 4;
      f32x4 a = acc[it][jt];
      ushort4 o;
      o.x = f2bf_u(a.x + bj); o.y = f2bf_u(a.y + bj);
      o.z = f2bf_u(a.z + bj); o.w = f2bf_u(a.w + bj);
      *(ushort4*)&vlt[(size_t)j * 8192 + i] = o;
    }
  }
}

// ---------------------------------------------------------------------------
// attn: C = P' @ VL^T-slice, full K=2048, plain store epilogue (invZ already
// folded into P'). 512 blocks, 128x128 tile, BK=32.
// XCD swizzle: xcd = id&7 handles s-tiles [xcd*8, xcd*8+8) x all 8 h-tiles
// -> per-XCD L2 set ~ 4MB P + 4MB vlt of ONE batch.
// ---------------------------------------------------------------------------
__global__ void __launch_bounds__(256) attn(
    const unsigned short* __restrict__ p, const unsigned short* __restrict__ vlt,
    float* __restrict__ out) {
  __shared__ __align__(16) char sA[128 * 64];
  __shared__ __align__(16) char sB[128 * 64];
  int tid = threadIdx.x;
  int lane = tid & 63, wave = tid >> 6;
  int pid = blockIdx.x;
  int xcd = pid & 7, kk = pid >> 3;
  int i0 = (xcd * 8 + (kk >> 3)) * 128;  // s-row tile (batch-major)
  int h0 = (kk & 7) * 128;               // h tile
  int b = i0 >> 11;
  size_t toff = (size_t)b << 11;
  int sr = lane >> 2, sc = lane & 3;
  int wr = wave >> 1, wc = wave & 1;
  int m_ = lane & 15, q = lane >> 4;
  int e = (m_ >> 1) & 3;
  const char* arp = sA + ((wr * 64 + m_) * 64) + ((q ^ e) * 16);
  const char* brp = sB + ((wc * 64 + m_) * 64) + ((q ^ e) * 16);
  f32x4 acc[4][4] = {};
  for (int k0 = 0; k0 < 2048; k0 += 32) {
    __syncthreads();
#pragma unroll
    for (int ii = 0; ii < 2; ++ii) {
      int r0 = wave * 32 + ii * 16;
      int r = r0 + sr;
      int cg = sc ^ ((r >> 1) & 3);
      g2lds16(p + ((size_t)(i0 + r) * 2048 + k0 + cg * 8), sA + r0 * 64);
      g2lds16(vlt + ((size_t)(h0 + r) * 8192 + toff + k0 + cg * 8), sB + r0 * 64);
    }
    __syncthreads();
    bf16x8 af[4], bfr[4];
#pragma unroll
    for (int i = 0; i < 4; ++i) af[i] = *(const bf16x8*)(arp + i * 1024);
#pragma unroll
    for (int j = 0; j < 4; ++j) bfr[j] = *(const bf16x8*)(brp + j * 1024);
#pragma unroll
    for (int i = 0; i < 4; ++i)
#pragma unroll
      for (int j = 0; j < 4; ++j)
        acc[i][j] = __builtin_amdgcn_mfma_f32_16x16x32_bf16(af[i], bfr[j], acc[i][j], 0, 0, 0);
  }
#pragma unroll
  for (int it = 0; it < 4; ++it) {
    int gi = i0 + wr * 64 + it * 16 + q * 4;
#pragma unroll
    for (int jt = 0; jt < 4; ++jt) {
      int h = h0 + wc * 64 + jt * 16 + m_;
      f32x4 a = acc[it][jt];
      out[(size_t)(gi + 0) * 1024 + h] = a.x;
      out[(size_t)(gi + 1) * 1024 + h] = a.y;
      out[(size_t)(gi + 2) * 1024 + h] = a.z;
      out[(size_t)(gi + 3) * 1024 + h] = a.w;
    }
  }
}

// ---------------------------------------------------------------------------
// ws layout (peak ~50.5 MB):
//   [0, 33.5MB)        P' (bf16) -- overlaps hbf[0,16MB)+wbf[16,18MB), which
//                                   die after gemm_vl; statsP runs after.
//   [33.5MB, 50.3MB)   vlt (bf16, [1024][8192])
//   [50.3MB, 50.5MB)   aL, vArr, mL (3 x 32KB fp32)
// ---------------------------------------------------------------------------
extern "C" void kernel_launch(void* const* d_in, const int* in_sizes, int n_in,
                              void* d_out, int out_size, void* d_ws, size_t ws_size,
                              hipStream_t stream) {
  const float* hidden = (const float*)d_in[0];
  const float* mask   = (const float*)d_in[1];
  const float* vw     = (const float*)d_in[2];
  const float* vb     = (const float*)d_in[3];
  const float* U      = (const float*)d_in[4];
  const float* V      = (const float*)d_in[5];
  float* out = (float*)d_out;
  char* ws = (char*)d_ws;

  unsigned short* P   = (unsigned short*)ws;                   // 33,554,432 B
  unsigned short* hbf = (unsigned short*)ws;                   // dies before P written
  unsigned short* wbf = (unsigned short*)(ws + 16777216);      // dies before P written
  unsigned short* vlt = (unsigned short*)(ws + 33554432);      // 16,777,216 B
  float* aL   = (float*)(ws + 50331648);
  float* vArr = aL + 8192;
  float* mLa  = vArr + 8192;

  prep_hidden<<<8192, 256, 0, stream>>>(hidden, U, V, hbf, aL, vArr);
  prep_w<<<1024, 256, 0, stream>>>(vw, wbf);
  prep_mask<<<32, 256, 0, stream>>>(mask, mLa);
  gemm_vl<<<512, 256, 0, stream>>>(hbf, wbf, vb, vlt);
  statsP<<<8192, 256, 0, stream>>>(aL, vArr, mLa, P);
  attn<<<512, 256, 0, stream>>>(P, vlt, out);
}